// Round 19
// baseline (248.034 us; speedup 1.0000x reference)
//
#include <hip/hip_runtime.h>
#include <math.h>

typedef _Float16 f16;
typedef f16 f16x8 __attribute__((ext_vector_type(8)));
typedef float f32x4 __attribute__((ext_vector_type(4)));

#define N_ROWS 32768
#define DIM    256
#define KCODES 4096

// ws layout (float units)
#define WS_ET    0                           // et [4096][256] f32        (4 MB)
#define WS_BN    (WS_ET + KCODES*DIM)        // code norms [4096]
#define WS_AN    (WS_BN + KCODES)            // row norms [32768]
#define WS_PART  (WS_AN + N_ROWS)            // loss partials [8192]
#define WS_IDX   (WS_PART + 8192)            // argmin idx [32768] (int)
#define WS_BP    (WS_IDX + N_ROWS)           // B' images  4 MB = 1048576 floats
#define WS_AP    (WS_BP + 1048576)           // A' images 32 MB = 8388608 floats

// A'/B' geometry (R6/R9, proven): chunk = [128 rows][64 f16 = 128 B], swizzled
//   byte_in_row = (dd*2) ^ ((row & 7) << 4).
// Per-128-row A' block: 131072 B (H: 4 chunks x 16384 @0; L @65536)
// Per-128-code B' block: 131072 B (EH @0; EL @65536)
// sim*2^20 = H.EH + H.EL + L.EH (l*l dropped, ~4e-7 in dist units)
//
// R19 = R18 with setprio REMOVED from the MFMA cluster. s_setprio is a
// scheduling-region boundary; it split MFMAs and ds_reads into separate
// regions, making R18's sched_group_barrier interleave inert (exact-null
// result). With the boundary gone, SGB can emit {MFMA x4, DS_READ x1-2} x4
// so reads drain on the LDS pipe inside the matrix-pipe shadow.
// Schedule-only change: absmax must print exactly 2.441406e-4.

// ---------------------------------------------------------------- helpers
__device__ __forceinline__ void gload16(const void* g, void* l) {
#if __has_builtin(__builtin_amdgcn_global_load_lds)
    __builtin_amdgcn_global_load_lds(
        (const __attribute__((address_space(1))) unsigned int*)g,
        (__attribute__((address_space(3))) unsigned int*)l, 16, 0, 0);
#else
    *(float4*)l = *(const float4*)g;
#endif
}

// ---------------------------------------------------------------- row norms (codes)
__global__ void vq_rownorm(const float* __restrict__ src, float* __restrict__ out, int nrows) {
    int w    = threadIdx.x >> 6;
    int lane = threadIdx.x & 63;
    int row  = blockIdx.x * 4 + w;
    if (row >= nrows) return;
    float4 v = *(const float4*)&src[row * DIM + lane * 4];
    float  s = v.x * v.x + v.y * v.y + v.z * v.z + v.w * v.w;
#pragma unroll
    for (int m = 1; m < 64; m <<= 1) s += __shfl_xor(s, m);
    if (lane == 0) out[row] = s;
}

// ---------------------------------------------------------------- A' prep (+ fused x row norms)
__global__ void vq_prep_a(const float* __restrict__ x, char* __restrict__ Ap,
                          float* __restrict__ An) {
    const int t = threadIdx.x;
    const int lane = t & 63, w = t >> 6;
    const size_t row0 = (size_t)blockIdx.x * 128;
    char* base = Ap + (size_t)blockIdx.x * 131072;
    const int chunk = lane >> 4;
    const int dd2   = (lane & 15) * 8;
#pragma unroll 4
    for (int it = 0; it < 32; ++it) {
        const int m = it * 4 + w;
        float4 v = *(const float4*)&x[(row0 + m) * DIM + lane * 4];
        float vs[4] = { v.x, v.y, v.z, v.w };
        uint32_t hw[2], lw[2];
#pragma unroll
        for (int p = 0; p < 2; ++p) {
            uint32_t hword = 0, lword = 0;
#pragma unroll
            for (int j = 0; j < 2; ++j) {
                float s = vs[p * 2 + j] * 1024.0f;
                f16 h = (f16)s;
                f16 l = (f16)(s - (float)h);
                hword |= (uint32_t)__builtin_bit_cast(uint16_t, h) << (16 * j);
                lword |= (uint32_t)__builtin_bit_cast(uint16_t, l) << (16 * j);
            }
            hw[p] = hword; lw[p] = lword;
        }
        const int off = chunk * 16384 + m * 128 + (dd2 ^ ((m & 7) << 4));
        *(uint2*)(base + off)         = *(uint2*)hw;
        *(uint2*)(base + 65536 + off) = *(uint2*)lw;
        float s = v.x * v.x + v.y * v.y + v.z * v.z + v.w * v.w;
#pragma unroll
        for (int mm = 1; mm < 64; mm <<= 1) s += __shfl_xor(s, mm);
        if (lane == 0) An[row0 + m] = s;
    }
}

// ---------------------------------------------------------------- B' prep (+ writes et)
__global__ void vq_prep_b(const float* __restrict__ e, char* __restrict__ Bp,
                          float* __restrict__ et) {
    __shared__ float lt[128][65];
    const int t  = threadIdx.x;
    const int jb = blockIdx.x >> 2;
    const int c  = blockIdx.x & 3;
    const int d0 = c * 64, n0 = jb * 128;
#pragma unroll
    for (int it = 0; it < 8; ++it) {
        int linear = it * 256 + t;
        int drow = linear >> 5;
        int ncol = (linear & 31) * 4;
        float4 v = *(const float4*)&e[(size_t)(d0 + drow) * KCODES + n0 + ncol];
        lt[ncol + 0][drow] = v.x;
        lt[ncol + 1][drow] = v.y;
        lt[ncol + 2][drow] = v.z;
        lt[ncol + 3][drow] = v.w;
    }
    __syncthreads();
#pragma unroll
    for (int it = 0; it < 8; ++it) {
        int lin = it * 256 + t;
        int n = lin >> 4, q = lin & 15;
        float4 v = { lt[n][q*4], lt[n][q*4+1], lt[n][q*4+2], lt[n][q*4+3] };
        *(float4*)&et[(size_t)(n0 + n) * DIM + d0 + q * 4] = v;
    }
    char* ehbase = Bp + (size_t)jb * 131072 + c * 16384;
    const int n_loc = t >> 1;
    const int shalf = t & 1;
#pragma unroll
    for (int g = 0; g < 4; ++g) {
        const int dd8 = shalf * 32 + g * 8;
        uint32_t ehw[4], elw[4];
#pragma unroll
        for (int p = 0; p < 4; ++p) {
            uint32_t hword = 0, lword = 0;
#pragma unroll
            for (int j = 0; j < 2; ++j) {
                float s = lt[n_loc][dd8 + p * 2 + j] * 1024.0f;
                f16 h = (f16)s;
                f16 l = (f16)(s - (float)h);
                hword |= (uint32_t)__builtin_bit_cast(uint16_t, h) << (16 * j);
                lword |= (uint32_t)__builtin_bit_cast(uint16_t, l) << (16 * j);
            }
            ehw[p] = hword; elw[p] = lword;
        }
        const int off = n_loc * 128 + ((dd8 * 2) ^ ((n_loc & 7) << 4));
        *(uint4*)(ehbase + off)         = *(uint4*)ehw;
        *(uint4*)(ehbase + 65536 + off) = *(uint4*)elw;
    }
}

// ---------------------------------------------------------------- main MFMA GEMM + argmin
// Grid 256 (1 block/CU), 512 thr, 8 waves (2 wr x 4 wc), block owns 128 rows.
// 64 steps x 6 fine phases (R15) + SGB interleave, no setprio boundaries.
__global__ __launch_bounds__(512, 1) void vq_main(
    const char* __restrict__ Ap, const char* __restrict__ Bp,
    const float* __restrict__ An, const float* __restrict__ Bn,
    int* __restrict__ idxOut)
{
    __shared__ __align__(16) char LaH[2][16384];
    __shared__ __align__(16) char LaL[2][16384];
    __shared__ __align__(16) char LbEH[2][32768];
    __shared__ __align__(16) char LbEL[32768];   // single; red[] overlays after loop
    // total 163840 B = 160 KiB exactly

    const int tid = threadIdx.x;
    const int wid = tid >> 6, lane = tid & 63;
    const int wr = wid >> 2, wc = wid & 3;            // 2 x 4 waves
    const int hi = lane >> 4, ln = lane & 15;
    const int sx = (lane & 7) << 4;
    const int ko0 = (hi * 16) ^ sx;
    const int ko1 = (64 + hi * 16) ^ sx;
    const size_t row0 = (size_t)blockIdx.x * 128;
    const char* abase = Ap + (size_t)blockIdx.x * 131072;

    float an[16];
#pragma unroll
    for (int mi = 0; mi < 4; ++mi)
#pragma unroll
        for (int r = 0; r < 4; ++r)
            an[mi * 4 + r] = An[row0 + wr * 64 + mi * 16 + hi * 4 + r];

    unsigned long long run[16];
#pragma unroll
    for (int v = 0; v < 16; ++v) run[v] = ~0ull;

#define ISSUE_E1(tn)                                                          \
    do {                                                                      \
        const int c_ = (tn) & 3, sl_ = (tn) & 1;                              \
        gload16(abase + c_ * 16384 + tid * 16,        LaH[sl_] + tid * 16);   \
        gload16(abase + c_ * 16384 + 8192 + tid * 16,                         \
                LaH[sl_] + 8192 + tid * 16);                                  \
        gload16(abase + 65536 + c_ * 16384 + tid * 16, LaL[sl_] + tid * 16);  \
        gload16(abase + 65536 + c_ * 16384 + 8192 + tid * 16,                 \
                LaL[sl_] + 8192 + tid * 16);                                  \
    } while (0)

#define ISSUE_E2(tn)                                                          \
    do {                                                                      \
        const int c_ = (tn) & 3, it_ = (tn) >> 2, sl_ = (tn) & 1;             \
        const char* b0_ = Bp + (size_t)(2 * it_) * 131072;                    \
        const char* b1_ = b0_ + 131072;                                       \
        gload16(b0_ + c_ * 16384 + tid * 16,        LbEH[sl_] + tid * 16);    \
        gload16(b0_ + c_ * 16384 + 8192 + tid * 16,                           \
                LbEH[sl_] + 8192 + tid * 16);                                 \
        gload16(b1_ + c_ * 16384 + tid * 16,                                  \
                LbEH[sl_] + 16384 + tid * 16);                                \
        gload16(b1_ + c_ * 16384 + 8192 + tid * 16,                           \
                LbEH[sl_] + 24576 + tid * 16);                                \
    } while (0)

#define ISSUE_L(tn)                                                           \
    do {                                                                      \
        const int c_ = (tn) & 3, it_ = (tn) >> 2;                             \
        const char* b0_ = Bp + (size_t)(2 * it_) * 131072;                    \
        const char* b1_ = b0_ + 131072;                                       \
        gload16(b0_ + 65536 + c_ * 16384 + tid * 16,        LbEL + tid * 16); \
        gload16(b0_ + 65536 + c_ * 16384 + 8192 + tid * 16,                   \
                LbEL + 8192 + tid * 16);                                      \
        gload16(b1_ + 65536 + c_ * 16384 + tid * 16,                          \
                LbEL + 16384 + tid * 16);                                     \
        gload16(b1_ + 65536 + c_ * 16384 + 8192 + tid * 16,                   \
                LbEL + 24576 + tid * 16);                                     \
    } while (0)

#define READ_A(dst, buf, koo)                                                 \
    _Pragma("unroll")                                                         \
    for (int i_ = 0; i_ < 4; ++i_)                                            \
        dst[i_] = *(const f16x8*)((buf) + (wr * 64 + i_ * 16 + ln) * 128 + (koo));

#define READ_B(dst, buf, koo)                                                 \
    _Pragma("unroll")                                                         \
    for (int n_ = 0; n_ < 4; ++n_)                                            \
        dst[n_] = *(const f16x8*)((buf) + ((wc & 1) * 64 + n_ * 16 + ln) * 128 + (koo));

#define LGKM_FENCE()                                                          \
    asm volatile("s_waitcnt lgkmcnt(0)" ::: "memory");                        \
    __builtin_amdgcn_sched_barrier(0)

// MFMA cluster WITHOUT setprio (setprio = scheduling-region boundary that
// made R18's SGB inert)
#define MFMA16(A, B)                                                          \
    _Pragma("unroll")                                                         \
    for (int mi_ = 0; mi_ < 4; ++mi_)                                         \
        _Pragma("unroll")                                                     \
        for (int ni_ = 0; ni_ < 4; ++ni_)                                     \
            acc[mi_][ni_] = __builtin_amdgcn_mfma_f32_16x16x32_f16(           \
                A[mi_], B[ni_], acc[mi_][ni_], 0, 0, 0)

// T19: force emitted order {MFMA x4, DS_READ xR} x4 within this sched region
#define SGB_INTERLEAVE(R)                                                     \
    _Pragma("unroll")                                                         \
    for (int q_ = 0; q_ < 4; ++q_) {                                          \
        __builtin_amdgcn_sched_group_barrier(0x008, 4, 0);  /* MFMA    */     \
        __builtin_amdgcn_sched_group_barrier(0x100, (R), 0);/* DS_READ */     \
    }

    f32x4 acc[4][4] = {};
    f16x8 aH0[4], aH1[4], bH0[4], bH1[4], bl[4], al[4];

    // prologue: stage step 0 (E1,E2 then L), wait E1/E2, read P0 frags
    ISSUE_E1(0);
    ISSUE_E2(0);
    ISSUE_L(0);
    asm volatile("s_waitcnt vmcnt(4)" ::: "memory");
    __builtin_amdgcn_s_barrier();
    READ_A(aH0, LaH[0], ko0);
    READ_B(bH0, LbEH[0] + (wc >> 1) * 16384, ko0);

#pragma unroll 1
    for (int t = 0; t < 64; ++t) {
        const int s  = t & 1;
        const int tn = (t + 1) & 63;
        const int sn = tn & 1;
        const char* aHb = LaH[s];
        const char* aLb = LaL[s];
        const char* bHb = LbEH[s] + (wc >> 1) * 16384;
        const char* bLb = LbEL + (wc >> 1) * 16384;

        // ---- P0: MFMA H.EH ks0 ; reads ks1 A/B ; issue E1(t+1)
        __builtin_amdgcn_s_barrier();
        ISSUE_E1(tn);
        LGKM_FENCE();
        MFMA16(aH0, bH0);
        READ_A(aH1, aHb, ko1);
        READ_B(bH1, bHb, ko1);
        SGB_INTERLEAVE(2);

        // ---- P1: MFMA H.EH ks1 ; reads bL ks0 ; issue E2(t+1)
        asm volatile("s_waitcnt vmcnt(4)" ::: "memory");   // L(t) landed
        __builtin_amdgcn_s_barrier();
        ISSUE_E2(tn);
        LGKM_FENCE();
        MFMA16(aH1, bH1);
        READ_B(bl, bLb, ko0);
        SGB_INTERLEAVE(1);

        // ---- P2: MFMA H.EL ks0 ; reads bL ks1
        __builtin_amdgcn_s_barrier();
        LGKM_FENCE();
        MFMA16(aH0, bl);
        READ_B(bl, bLb, ko1);
        SGB_INTERLEAVE(1);

        // ---- P3: MFMA H.EL ks1 ; reads aL ks0
        __builtin_amdgcn_s_barrier();
        LGKM_FENCE();
        MFMA16(aH1, bl);
        READ_A(al, aLb, ko0);
        SGB_INTERLEAVE(1);

        // ---- P4: MFMA L.EH ks0 ; reads aL ks1 ; issue L(t+1)
        __builtin_amdgcn_s_barrier();
        ISSUE_L(tn);
        LGKM_FENCE();
        MFMA16(al, bH0);
        READ_A(al, aLb, ko1);
        SGB_INTERLEAVE(1);

        // ---- P5: MFMA L.EH ks1 ; reads next step's ks0 A/B
        asm volatile("s_waitcnt vmcnt(4)" ::: "memory");   // E1,E2(t+1) landed
        __builtin_amdgcn_s_barrier();
        LGKM_FENCE();
        MFMA16(al, bH1);
        READ_A(aH0, LaH[sn], ko0);
        READ_B(bH0, LbEH[sn] + (wc >> 1) * 16384, ko0);
        SGB_INTERLEAVE(2);

        // ---- per-iter argmin epilogue
        if ((t & 3) == 3) {
            const int it = t >> 2;
            float bn[4];
#pragma unroll
            for (int ni = 0; ni < 4; ++ni)
                bn[ni] = Bn[it * 256 + wc * 64 + ni * 16 + ln];
#pragma unroll
            for (int mi = 0; mi < 4; ++mi)
#pragma unroll
                for (int r = 0; r < 4; ++r) {
                    const float a = an[mi * 4 + r];
                    unsigned long long best = run[mi * 4 + r];
#pragma unroll
                    for (int ni = 0; ni < 4; ++ni) {
                        float sim  = acc[mi][ni][r] * 0x1p-20f;
                        float tt   = a + bn[ni];
                        float dist = tt - 2.0f * sim;
                        unsigned code = (unsigned)(it * 256 + wc * 64 + ni * 16 + ln);
                        unsigned long long p =
                            ((unsigned long long)__float_as_uint(dist) << 32) | code;
                        best = p < best ? p : best;
                    }
                    run[mi * 4 + r] = best;
                }
#pragma unroll
            for (int mi = 0; mi < 4; ++mi)
#pragma unroll
                for (int ni = 0; ni < 4; ++ni)
                    acc[mi][ni] = f32x4{0.f, 0.f, 0.f, 0.f};
        }
    }
#undef ISSUE_E1
#undef ISSUE_E2
#undef ISSUE_L
#undef READ_A
#undef READ_B
#undef LGKM_FENCE
#undef MFMA16
#undef SGB_INTERLEAVE

    // ---- final reduce: over ln (codes within wave), then over wc via LDS
#pragma unroll
    for (int v = 0; v < 16; ++v) {
#pragma unroll
        for (int m = 1; m < 16; m <<= 1) {
            unsigned long long o = __shfl_xor(run[v], m);
            run[v] = o < run[v] ? o : run[v];
        }
    }
    __syncthreads();   // drains all outstanding; bEL region now dead
    unsigned long long (*red)[4] = (unsigned long long (*)[4])LbEL;
    if (ln == 0) {
#pragma unroll
        for (int mi = 0; mi < 4; ++mi)
#pragma unroll
            for (int r = 0; r < 4; ++r)
                red[wr * 64 + mi * 16 + hi * 4 + r][wc] = run[mi * 4 + r];
    }
    __syncthreads();
    if (tid < 128) {
        unsigned long long b = red[tid][0];
#pragma unroll
        for (int w = 1; w < 4; ++w) {
            unsigned long long o = red[tid][w];
            b = o < b ? o : b;
        }
        idxOut[row0 + tid] = (int)(unsigned)(b & 0xffffffffull);
    }
}

// ---------------------------------------------------------------- gather + loss partials
__global__ void vq_gather(const float* __restrict__ x, const float* __restrict__ et,
                          const int* __restrict__ idx,
                          float* __restrict__ out, float* __restrict__ part) {
    __shared__ float wsum[4];
    int w    = threadIdx.x >> 6;
    int lane = threadIdx.x & 63;
    int row  = blockIdx.x * 4 + w;
    int k    = idx[row];
    float4 q  = *(const float4*)&et[(size_t)k * DIM + lane * 4];
    float4 xv = *(const float4*)&x[(size_t)row * DIM + lane * 4];
    *(float4*)&out[(size_t)row * DIM + lane * 4] = q;
    float d0 = q.x - xv.x, d1 = q.y - xv.y, d2 = q.z - xv.z, d3 = q.w - xv.w;
    float s = d0 * d0 + d1 * d1 + d2 * d2 + d3 * d3;
#pragma unroll
    for (int m = 1; m < 64; m <<= 1) s += __shfl_xor(s, m);
    if (lane == 0) wsum[w] = s;
    __syncthreads();
    if (threadIdx.x == 0) part[blockIdx.x] = wsum[0] + wsum[1] + wsum[2] + wsum[3];
}

// ---------------------------------------------------------------- finalize loss
__global__ void vq_finalize(const float* __restrict__ part, float* __restrict__ lossOut) {
    __shared__ float sm[256];
    float s = 0.0f;
    for (int i = threadIdx.x; i < 8192; i += 256) s += part[i];
    sm[threadIdx.x] = s;
    __syncthreads();
    for (int st = 128; st > 0; st >>= 1) {
        if (threadIdx.x < st) sm[threadIdx.x] += sm[threadIdx.x + st];
        __syncthreads();
    }
    if (threadIdx.x == 0)
        lossOut[0] = 1.25f * (sm[0] / 8388608.0f);
}

// ---------------------------------------------------------------- launch
extern "C" void kernel_launch(void* const* d_in, const int* in_sizes, int n_in,
                              void* d_out, int out_size, void* d_ws, size_t ws_size,
                              hipStream_t stream) {
    const float* x = (const float*)d_in[0];   // [32768, 256]
    const float* e = (const float*)d_in[1];   // [256, 4096]
    float* out = (float*)d_out;
    float* ws  = (float*)d_ws;

    float* et   = ws + WS_ET;
    float* bn   = ws + WS_BN;
    float* an   = ws + WS_AN;
    float* part = ws + WS_PART;
    int*   idx  = (int*)(ws + WS_IDX);
    char*  Bp   = (char*)(ws + WS_BP);
    char*  Ap   = (char*)(ws + WS_AP);

    vq_prep_a<<<256, 256, 0, stream>>>(x, Ap, an);
    vq_prep_b<<<128, 256, 0, stream>>>(e, Bp, et);
    vq_rownorm<<<KCODES / 4, 256, 0, stream>>>(et, bn, KCODES);
    vq_main<<<256, 512, 0, stream>>>(Ap, Bp, an, bn, idx);
    vq_gather<<<N_ROWS / 4, 256, 0, stream>>>(x, et, idx, out, part);
    vq_finalize<<<1, 256, 0, stream>>>(part, out + (size_t)N_ROWS * DIM);
}

// Round 20
// 242.040 us; speedup vs baseline: 1.0248x; 1.0248x over previous
//
#include <hip/hip_runtime.h>
#include <math.h>

typedef _Float16 f16;
typedef f16 f16x8 __attribute__((ext_vector_type(8)));
typedef float f32x4 __attribute__((ext_vector_type(4)));

#define N_ROWS 32768
#define DIM    256
#define KCODES 4096

// ws layout (float units)
#define WS_ET    0                           // et [4096][256] f32        (4 MB)
#define WS_BN    (WS_ET + KCODES*DIM)        // code norms [4096]
#define WS_AN    (WS_BN + KCODES)            // row norms [32768]
#define WS_PART  (WS_AN + N_ROWS)            // loss partials [8192]
#define WS_IDX   (WS_PART + 8192)            // argmin idx [32768] (int)
#define WS_BP    (WS_IDX + N_ROWS)           // B' images  4 MB = 1048576 floats
#define WS_AP    (WS_BP + 1048576)           // A' images 32 MB = 8388608 floats

// A'/B' geometry (R6/R9, proven): chunk = [128 rows][64 f16 = 128 B], swizzled
//   byte_in_row = (dd*2) ^ ((row & 7) << 4).
// Per-128-row A' block: 131072 B (H: 4 chunks x 16384 @0; L @65536)
// Per-128-code B' block: 131072 B (EH @0; EL @65536)
// sim*2^20 = H.EH + H.EL + L.EH (l*l dropped, ~4e-7 in dist units)
//
// R20 = R18 with the three non-load-bearing barriers (P0, P2, P3) removed
// so waves desync within a step and one wave's ds_reads overlap the SIMD-
// mate's MFMAs. Load-bearing syncs kept: P1 {vmcnt(4)+bar} for L(t)
// visibility, P4 {bar} for the LbEL WAR, P5 {vmcnt(4); lgkm-fence; bar}
// for E1/E2(t+1) visibility AND to certify P4-end al-reads complete before
// P0's ISSUE_E1 overwrite (fence moved BEFORE the barrier for that).
// Per-wave issue order, vmcnt ledger, accumulation order unchanged
// -> absmax must print exactly 2.441406e-4.

// ---------------------------------------------------------------- helpers
__device__ __forceinline__ void gload16(const void* g, void* l) {
#if __has_builtin(__builtin_amdgcn_global_load_lds)
    __builtin_amdgcn_global_load_lds(
        (const __attribute__((address_space(1))) unsigned int*)g,
        (__attribute__((address_space(3))) unsigned int*)l, 16, 0, 0);
#else
    *(float4*)l = *(const float4*)g;
#endif
}

// ---------------------------------------------------------------- row norms (codes)
__global__ void vq_rownorm(const float* __restrict__ src, float* __restrict__ out, int nrows) {
    int w    = threadIdx.x >> 6;
    int lane = threadIdx.x & 63;
    int row  = blockIdx.x * 4 + w;
    if (row >= nrows) return;
    float4 v = *(const float4*)&src[row * DIM + lane * 4];
    float  s = v.x * v.x + v.y * v.y + v.z * v.z + v.w * v.w;
#pragma unroll
    for (int m = 1; m < 64; m <<= 1) s += __shfl_xor(s, m);
    if (lane == 0) out[row] = s;
}

// ---------------------------------------------------------------- A' prep (+ fused x row norms)
__global__ void vq_prep_a(const float* __restrict__ x, char* __restrict__ Ap,
                          float* __restrict__ An) {
    const int t = threadIdx.x;
    const int lane = t & 63, w = t >> 6;
    const size_t row0 = (size_t)blockIdx.x * 128;
    char* base = Ap + (size_t)blockIdx.x * 131072;
    const int chunk = lane >> 4;
    const int dd2   = (lane & 15) * 8;
#pragma unroll 4
    for (int it = 0; it < 32; ++it) {
        const int m = it * 4 + w;
        float4 v = *(const float4*)&x[(row0 + m) * DIM + lane * 4];
        float vs[4] = { v.x, v.y, v.z, v.w };
        uint32_t hw[2], lw[2];
#pragma unroll
        for (int p = 0; p < 2; ++p) {
            uint32_t hword = 0, lword = 0;
#pragma unroll
            for (int j = 0; j < 2; ++j) {
                float s = vs[p * 2 + j] * 1024.0f;
                f16 h = (f16)s;
                f16 l = (f16)(s - (float)h);
                hword |= (uint32_t)__builtin_bit_cast(uint16_t, h) << (16 * j);
                lword |= (uint32_t)__builtin_bit_cast(uint16_t, l) << (16 * j);
            }
            hw[p] = hword; lw[p] = lword;
        }
        const int off = chunk * 16384 + m * 128 + (dd2 ^ ((m & 7) << 4));
        *(uint2*)(base + off)         = *(uint2*)hw;
        *(uint2*)(base + 65536 + off) = *(uint2*)lw;
        float s = v.x * v.x + v.y * v.y + v.z * v.z + v.w * v.w;
#pragma unroll
        for (int mm = 1; mm < 64; mm <<= 1) s += __shfl_xor(s, mm);
        if (lane == 0) An[row0 + m] = s;
    }
}

// ---------------------------------------------------------------- B' prep (+ writes et)
__global__ void vq_prep_b(const float* __restrict__ e, char* __restrict__ Bp,
                          float* __restrict__ et) {
    __shared__ float lt[128][65];
    const int t  = threadIdx.x;
    const int jb = blockIdx.x >> 2;
    const int c  = blockIdx.x & 3;
    const int d0 = c * 64, n0 = jb * 128;
#pragma unroll
    for (int it = 0; it < 8; ++it) {
        int linear = it * 256 + t;
        int drow = linear >> 5;
        int ncol = (linear & 31) * 4;
        float4 v = *(const float4*)&e[(size_t)(d0 + drow) * KCODES + n0 + ncol];
        lt[ncol + 0][drow] = v.x;
        lt[ncol + 1][drow] = v.y;
        lt[ncol + 2][drow] = v.z;
        lt[ncol + 3][drow] = v.w;
    }
    __syncthreads();
#pragma unroll
    for (int it = 0; it < 8; ++it) {
        int lin = it * 256 + t;
        int n = lin >> 4, q = lin & 15;
        float4 v = { lt[n][q*4], lt[n][q*4+1], lt[n][q*4+2], lt[n][q*4+3] };
        *(float4*)&et[(size_t)(n0 + n) * DIM + d0 + q * 4] = v;
    }
    char* ehbase = Bp + (size_t)jb * 131072 + c * 16384;
    const int n_loc = t >> 1;
    const int shalf = t & 1;
#pragma unroll
    for (int g = 0; g < 4; ++g) {
        const int dd8 = shalf * 32 + g * 8;
        uint32_t ehw[4], elw[4];
#pragma unroll
        for (int p = 0; p < 4; ++p) {
            uint32_t hword = 0, lword = 0;
#pragma unroll
            for (int j = 0; j < 2; ++j) {
                float s = lt[n_loc][dd8 + p * 2 + j] * 1024.0f;
                f16 h = (f16)s;
                f16 l = (f16)(s - (float)h);
                hword |= (uint32_t)__builtin_bit_cast(uint16_t, h) << (16 * j);
                lword |= (uint32_t)__builtin_bit_cast(uint16_t, l) << (16 * j);
            }
            ehw[p] = hword; elw[p] = lword;
        }
        const int off = n_loc * 128 + ((dd8 * 2) ^ ((n_loc & 7) << 4));
        *(uint4*)(ehbase + off)         = *(uint4*)ehw;
        *(uint4*)(ehbase + 65536 + off) = *(uint4*)elw;
    }
}

// ---------------------------------------------------------------- main MFMA GEMM + argmin
// Grid 256 (1 block/CU), 512 thr, 8 waves (2 wr x 4 wc), block owns 128 rows.
// 64 steps x 6 fine phases; barriers only at P1, P4, P5.
__global__ __launch_bounds__(512, 1) void vq_main(
    const char* __restrict__ Ap, const char* __restrict__ Bp,
    const float* __restrict__ An, const float* __restrict__ Bn,
    int* __restrict__ idxOut)
{
    __shared__ __align__(16) char LaH[2][16384];
    __shared__ __align__(16) char LaL[2][16384];
    __shared__ __align__(16) char LbEH[2][32768];
    __shared__ __align__(16) char LbEL[32768];   // single; red[] overlays after loop
    // total 163840 B = 160 KiB exactly

    const int tid = threadIdx.x;
    const int wid = tid >> 6, lane = tid & 63;
    const int wr = wid >> 2, wc = wid & 3;            // 2 x 4 waves
    const int hi = lane >> 4, ln = lane & 15;
    const int sx = (lane & 7) << 4;
    const int ko0 = (hi * 16) ^ sx;
    const int ko1 = (64 + hi * 16) ^ sx;
    const size_t row0 = (size_t)blockIdx.x * 128;
    const char* abase = Ap + (size_t)blockIdx.x * 131072;

    float an[16];
#pragma unroll
    for (int mi = 0; mi < 4; ++mi)
#pragma unroll
        for (int r = 0; r < 4; ++r)
            an[mi * 4 + r] = An[row0 + wr * 64 + mi * 16 + hi * 4 + r];

    unsigned long long run[16];
#pragma unroll
    for (int v = 0; v < 16; ++v) run[v] = ~0ull;

#define ISSUE_E1(tn)                                                          \
    do {                                                                      \
        const int c_ = (tn) & 3, sl_ = (tn) & 1;                              \
        gload16(abase + c_ * 16384 + tid * 16,        LaH[sl_] + tid * 16);   \
        gload16(abase + c_ * 16384 + 8192 + tid * 16,                         \
                LaH[sl_] + 8192 + tid * 16);                                  \
        gload16(abase + 65536 + c_ * 16384 + tid * 16, LaL[sl_] + tid * 16);  \
        gload16(abase + 65536 + c_ * 16384 + 8192 + tid * 16,                 \
                LaL[sl_] + 8192 + tid * 16);                                  \
    } while (0)

#define ISSUE_E2(tn)                                                          \
    do {                                                                      \
        const int c_ = (tn) & 3, it_ = (tn) >> 2, sl_ = (tn) & 1;             \
        const char* b0_ = Bp + (size_t)(2 * it_) * 131072;                    \
        const char* b1_ = b0_ + 131072;                                       \
        gload16(b0_ + c_ * 16384 + tid * 16,        LbEH[sl_] + tid * 16);    \
        gload16(b0_ + c_ * 16384 + 8192 + tid * 16,                           \
                LbEH[sl_] + 8192 + tid * 16);                                 \
        gload16(b1_ + c_ * 16384 + tid * 16,                                  \
                LbEH[sl_] + 16384 + tid * 16);                                \
        gload16(b1_ + c_ * 16384 + 8192 + tid * 16,                           \
                LbEH[sl_] + 24576 + tid * 16);                                \
    } while (0)

#define ISSUE_L(tn)                                                           \
    do {                                                                      \
        const int c_ = (tn) & 3, it_ = (tn) >> 2;                             \
        const char* b0_ = Bp + (size_t)(2 * it_) * 131072;                    \
        const char* b1_ = b0_ + 131072;                                       \
        gload16(b0_ + 65536 + c_ * 16384 + tid * 16,        LbEL + tid * 16); \
        gload16(b0_ + 65536 + c_ * 16384 + 8192 + tid * 16,                   \
                LbEL + 8192 + tid * 16);                                      \
        gload16(b1_ + 65536 + c_ * 16384 + tid * 16,                          \
                LbEL + 16384 + tid * 16);                                     \
        gload16(b1_ + 65536 + c_ * 16384 + 8192 + tid * 16,                   \
                LbEL + 24576 + tid * 16);                                     \
    } while (0)

#define READ_A(dst, buf, koo)                                                 \
    _Pragma("unroll")                                                         \
    for (int i_ = 0; i_ < 4; ++i_)                                            \
        dst[i_] = *(const f16x8*)((buf) + (wr * 64 + i_ * 16 + ln) * 128 + (koo));

#define READ_B(dst, buf, koo)                                                 \
    _Pragma("unroll")                                                         \
    for (int n_ = 0; n_ < 4; ++n_)                                            \
        dst[n_] = *(const f16x8*)((buf) + ((wc & 1) * 64 + n_ * 16 + ln) * 128 + (koo));

#define LGKM_FENCE()                                                          \
    asm volatile("s_waitcnt lgkmcnt(0)" ::: "memory");                        \
    __builtin_amdgcn_sched_barrier(0)

#define MFMA16(A, B)                                                          \
    __builtin_amdgcn_s_setprio(1);                                            \
    _Pragma("unroll")                                                         \
    for (int mi_ = 0; mi_ < 4; ++mi_)                                         \
        _Pragma("unroll")                                                     \
        for (int ni_ = 0; ni_ < 4; ++ni_)                                     \
            acc[mi_][ni_] = __builtin_amdgcn_mfma_f32_16x16x32_f16(           \
                A[mi_], B[ni_], acc[mi_][ni_], 0, 0, 0);                      \
    __builtin_amdgcn_s_setprio(0)

    f32x4 acc[4][4] = {};
    f16x8 aH0[4], aH1[4], bH0[4], bH1[4], bl[4], al[4];

    // prologue: stage step 0 (E1,E2 then L), wait E1/E2, read P0 frags
    ISSUE_E1(0);
    ISSUE_E2(0);
    ISSUE_L(0);
    asm volatile("s_waitcnt vmcnt(4)" ::: "memory");
    __builtin_amdgcn_s_barrier();
    READ_A(aH0, LaH[0], ko0);
    READ_B(bH0, LbEH[0] + (wc >> 1) * 16384, ko0);

#pragma unroll 1
    for (int t = 0; t < 64; ++t) {
        const int s  = t & 1;
        const int tn = (t + 1) & 63;
        const int sn = tn & 1;
        const char* aHb = LaH[s];
        const char* aLb = LaL[s];
        const char* bHb = LbEH[s] + (wc >> 1) * 16384;
        const char* bLb = LbEL + (wc >> 1) * 16384;

        // ---- P0 (no barrier): issue E1(t+1) ; MFMA H.EH ks0 ; reads ks1 A/B
        ISSUE_E1(tn);
        LGKM_FENCE();
        MFMA16(aH0, bH0);
        READ_A(aH1, aHb, ko1);
        READ_B(bH1, bHb, ko1);

        // ---- P1 (vmcnt+bar): MFMA H.EH ks1 ; reads bL ks0 ; issue E2(t+1)
        asm volatile("s_waitcnt vmcnt(4)" ::: "memory");   // L(t) landed (own)
        __builtin_amdgcn_s_barrier();                      // ...and all waves'
        ISSUE_E2(tn);
        LGKM_FENCE();
        MFMA16(aH1, bH1);
        READ_B(bl, bLb, ko0);

        // ---- P2 (no barrier): MFMA H.EL ks0 ; reads bL ks1
        LGKM_FENCE();
        MFMA16(aH0, bl);
        READ_B(bl, bLb, ko1);

        // ---- P3 (no barrier): MFMA H.EL ks1 ; reads aL ks0
        LGKM_FENCE();
        MFMA16(aH1, bl);
        READ_A(al, aLb, ko0);

        // ---- P4 (bar, WAR on LbEL): issue L(t+1) ; MFMA L.EH ks0 ; reads aL ks1
        __builtin_amdgcn_s_barrier();    // all waves' bl reads done (P3 fences)
        ISSUE_L(tn);
        LGKM_FENCE();
        MFMA16(al, bH0);
        READ_A(al, aLb, ko1);

        // ---- P5 (vmcnt + fence + bar): MFMA L.EH ks1 ; reads next ks0 A/B
        asm volatile("s_waitcnt vmcnt(4)" ::: "memory");   // E1,E2(t+1) landed
        asm volatile("s_waitcnt lgkmcnt(0)" ::: "memory"); // my aL-ks1 read done
        __builtin_amdgcn_sched_barrier(0);
        __builtin_amdgcn_s_barrier();    // all waves: loads visible, reads done
        MFMA16(al, bH1);
        READ_A(aH0, LaH[sn], ko0);
        READ_B(bH0, LbEH[sn] + (wc >> 1) * 16384, ko0);

        // ---- per-iter argmin epilogue
        if ((t & 3) == 3) {
            const int it = t >> 2;
            float bn[4];
#pragma unroll
            for (int ni = 0; ni < 4; ++ni)
                bn[ni] = Bn[it * 256 + wc * 64 + ni * 16 + ln];
#pragma unroll
            for (int mi = 0; mi < 4; ++mi)
#pragma unroll
                for (int r = 0; r < 4; ++r) {
                    const float a = an[mi * 4 + r];
                    unsigned long long best = run[mi * 4 + r];
#pragma unroll
                    for (int ni = 0; ni < 4; ++ni) {
                        float sim  = acc[mi][ni][r] * 0x1p-20f;
                        float tt   = a + bn[ni];
                        float dist = tt - 2.0f * sim;
                        unsigned code = (unsigned)(it * 256 + wc * 64 + ni * 16 + ln);
                        unsigned long long p =
                            ((unsigned long long)__float_as_uint(dist) << 32) | code;
                        best = p < best ? p : best;
                    }
                    run[mi * 4 + r] = best;
                }
#pragma unroll
            for (int mi = 0; mi < 4; ++mi)
#pragma unroll
                for (int ni = 0; ni < 4; ++ni)
                    acc[mi][ni] = f32x4{0.f, 0.f, 0.f, 0.f};
        }
    }
#undef ISSUE_E1
#undef ISSUE_E2
#undef ISSUE_L
#undef READ_A
#undef READ_B
#undef LGKM_FENCE
#undef MFMA16

    // ---- final reduce: over ln (codes within wave), then over wc via LDS
#pragma unroll
    for (int v = 0; v < 16; ++v) {
#pragma unroll
        for (int m = 1; m < 16; m <<= 1) {
            unsigned long long o = __shfl_xor(run[v], m);
            run[v] = o < run[v] ? o : run[v];
        }
    }
    __syncthreads();   // drains all outstanding; bEL region now dead
    unsigned long long (*red)[4] = (unsigned long long (*)[4])LbEL;
    if (ln == 0) {
#pragma unroll
        for (int mi = 0; mi < 4; ++mi)
#pragma unroll
            for (int r = 0; r < 4; ++r)
                red[wr * 64 + mi * 16 + hi * 4 + r][wc] = run[mi * 4 + r];
    }
    __syncthreads();
    if (tid < 128) {
        unsigned long long b = red[tid][0];
#pragma unroll
        for (int w = 1; w < 4; ++w) {
            unsigned long long o = red[tid][w];
            b = o < b ? o : b;
        }
        idxOut[row0 + tid] = (int)(unsigned)(b & 0xffffffffull);
    }
}

// ---------------------------------------------------------------- gather + loss partials
__global__ void vq_gather(const float* __restrict__ x, const float* __restrict__ et,
                          const int* __restrict__ idx,
                          float* __restrict__ out, float* __restrict__ part) {
    __shared__ float wsum[4];
    int w    = threadIdx.x >> 6;
    int lane = threadIdx.x & 63;
    int row  = blockIdx.x * 4 + w;
    int k    = idx[row];
    float4 q  = *(const float4*)&et[(size_t)k * DIM + lane * 4];
    float4 xv = *(const float4*)&x[(size_t)row * DIM + lane * 4];
    *(float4*)&out[(size_t)row * DIM + lane * 4] = q;
    float d0 = q.x - xv.x, d1 = q.y - xv.y, d2 = q.z - xv.z, d3 = q.w - xv.w;
    float s = d0 * d0 + d1 * d1 + d2 * d2 + d3 * d3;
#pragma unroll
    for (int m = 1; m < 64; m <<= 1) s += __shfl_xor(s, m);
    if (lane == 0) wsum[w] = s;
    __syncthreads();
    if (threadIdx.x == 0) part[blockIdx.x] = wsum[0] + wsum[1] + wsum[2] + wsum[3];
}

// ---------------------------------------------------------------- finalize loss
__global__ void vq_finalize(const float* __restrict__ part, float* __restrict__ lossOut) {
    __shared__ float sm[256];
    float s = 0.0f;
    for (int i = threadIdx.x; i < 8192; i += 256) s += part[i];
    sm[threadIdx.x] = s;
    __syncthreads();
    for (int st = 128; st > 0; st >>= 1) {
        if (threadIdx.x < st) sm[threadIdx.x] += sm[threadIdx.x + st];
        __syncthreads();
    }
    if (threadIdx.x == 0)
        lossOut[0] = 1.25f * (sm[0] / 8388608.0f);
}

// ---------------------------------------------------------------- launch
extern "C" void kernel_launch(void* const* d_in, const int* in_sizes, int n_in,
                              void* d_out, int out_size, void* d_ws, size_t ws_size,
                              hipStream_t stream) {
    const float* x = (const float*)d_in[0];   // [32768, 256]
    const float* e = (const float*)d_in[1];   // [256, 4096]
    float* out = (float*)d_out;
    float* ws  = (float*)d_ws;

    float* et   = ws + WS_ET;
    float* bn   = ws + WS_BN;
    float* an   = ws + WS_AN;
    float* part = ws + WS_PART;
    int*   idx  = (int*)(ws + WS_IDX);
    char*  Bp   = (char*)(ws + WS_BP);
    char*  Ap   = (char*)(ws + WS_AP);

    vq_prep_a<<<256, 256, 0, stream>>>(x, Ap, an);
    vq_prep_b<<<128, 256, 0, stream>>>(e, Bp, et);
    vq_rownorm<<<KCODES / 4, 256, 0, stream>>>(et, bn, KCODES);
    vq_main<<<256, 512, 0, stream>>>(Ap, Bp, an, bn, idx);
    vq_gather<<<N_ROWS / 4, 256, 0, stream>>>(x, et, idx, out, part);
    vq_finalize<<<1, 256, 0, stream>>>(part, out + (size_t)N_ROWS * DIM);
}